// Round 4
// baseline (412.695 us; speedup 1.0000x reference)
//
#include <hip/hip_runtime.h>
#include <hip/hip_bf16.h>

// CausalDiscoveryModule: B=256, N=512, E=32, IN=512, K=10
// out[b,i,j] = gate_b * sigmoid(logit) on per-(b,i)-row top-10 of j, else 0
// logit = sum_e (c_b^2 * emb_i)[e] * emb_j[e]
//
// R4: 4-way j-split. One block = 4 waves = one 64-row group; wave h scans
// j in [128h, 128h+128). All 4 top-10 lists published to LDS; every wave
// re-merges all 4 in h-order (exact jax tie semantics); epilogue distributed
// (wave w writes rows 16w..16w+15). LDS overlay 32KB -> 5 blocks/CU,
// 20 waves/CU. Per-logit FMA order bit-identical to R1/R3.

#define NUM_VARS 512
#define EMBED_DIM 32
#define IN_DIM 512
#define BATCH 256

typedef float nf4 __attribute__((ext_vector_type(4)));  // NT-store friendly

// ---------------- K1: context MLP -> w = c^2 [256][32], gate [256] ----------
__global__ __launch_bounds__(256) void cdm_k1(
    const float* __restrict__ ctx, const float* __restrict__ W1,
    const float* __restrict__ b1, const float* __restrict__ W2,
    const float* __restrict__ b2, const float* __restrict__ Wg,
    const float* __restrict__ bg, float* __restrict__ wws,
    float* __restrict__ gws) {
  const int bb = blockIdx.x;
  const int t = threadIdx.x;
  __shared__ float xs[512];
  __shared__ float psum[32][9];   // +1 pad
  __shared__ float hs[32];
  __shared__ float cs[32];
  const float* x = ctx + (bb << 9);
  xs[t] = x[t];
  xs[t + 256] = x[t + 256];
  __syncthreads();
  {
    const int e = t >> 3, part = t & 7;
    const float* wrow = W1 + e * 512 + part * 64;
    const float* xp = xs + part * 64;
    float a = 0.f;
#pragma unroll
    for (int m = 0; m < 64; ++m) a = fmaf(wrow[m], xp[m], a);
    psum[e][part] = a;
  }
  __syncthreads();
  if (t < 32) {
    float a = 0.f;
#pragma unroll
    for (int p = 0; p < 8; ++p) a += psum[t][p];
    hs[t] = fmaxf(a + b1[t], 0.f);
  }
  __syncthreads();
  if (t < 32) {
    const float* wrow = W2 + (t << 5);
    float a = 0.f;
#pragma unroll
    for (int k = 0; k < 32; ++k) a = fmaf(wrow[k], hs[k], a);
    float c = a + b2[t];
    cs[t] = c;
    wws[(bb << 5) + t] = c * c;
  }
  __syncthreads();
  if (t == 0) {
    float a = 0.f;
#pragma unroll
    for (int k = 0; k < 32; ++k) a = fmaf(Wg[k], cs[k], a);
    float g = a + bg[0];
    gws[bb] = 1.f / (1.f + __expf(-g));
  }
}

// strict-> shift insert: equal values keep earlier-inserted (lower j) above
#define TOP10_INSERT(av, aj, v, jn)                           \
  do {                                                        \
    _Pragma("unroll") for (int k = 9; k >= 1; --k) {          \
      bool gk = (v) > av[k];                                  \
      bool gk1 = (v) > av[k - 1];                             \
      av[k] = gk ? (gk1 ? av[k - 1] : (v)) : av[k];           \
      aj[k] = gk ? (gk1 ? aj[k - 1] : (jn)) : aj[k];          \
    }                                                         \
    bool g0 = (v) > av[0];                                    \
    av[0] = g0 ? (v) : av[0];                                 \
    aj[0] = g0 ? (jn) : aj[0];                                \
  } while (0)

// ---------------- K2: 4-wave block per 64 rows; exact top-10; masked write --
__global__ __launch_bounds__(256, 5) void cdm_k2(
    const float* __restrict__ emb, const float* __restrict__ wws,
    const float* __restrict__ gws, float* __restrict__ out) {
  const int lane = threadIdx.x & 63;
  const int w = threadIdx.x >> 6;    // j-quarter 0..3
  const int G = __builtin_amdgcn_readfirstlane(blockIdx.x);
  const int r0 = G << 6;             // 64 rows per block, same b
  const int b = r0 >> 9;
  const int i = (r0 + lane) & 511;
  const int jbase = __builtin_amdgcn_readfirstlane(w << 7);

  __shared__ float lds[8192];                      // 32 KB overlay
  float* mv = lds;                                 // [4][64][10] values
  int* mj = reinterpret_cast<int*>(lds + 2560);    // [4][64][10] indices

  // sv[e] = (c^2)[b][e] * emb[i][e]  (per-lane)
  float sv[32];
  {
    const float4* wb = reinterpret_cast<const float4*>(wws + (b << 5));
    const float4* ei = reinterpret_cast<const float4*>(emb + (i << 5));
#pragma unroll
    for (int q = 0; q < 8; ++q) {
      float4 a = wb[q];
      float4 xv = ei[q];
      sv[4 * q + 0] = a.x * xv.x;
      sv[4 * q + 1] = a.y * xv.y;
      sv[4 * q + 2] = a.z * xv.z;
      sv[4 * q + 3] = a.w * xv.w;
    }
  }
  const float gateb = gws[b];

  float hv[10];
  int hj[10];
#pragma unroll
  for (int k = 0; k < 10; ++k) { hv[k] = -1e30f; hj[k] = 0; }

  const float4* eb = reinterpret_cast<const float4*>(emb);
  for (int t = 0; t < 32; ++t) {
    const int j0 = jbase + (t << 2);
    float a0 = 0.f, a1 = 0.f, a2 = 0.f, a3 = 0.f;
    const float4* e0 = eb + ((j0 + 0) << 3);
    const float4* e1 = eb + ((j0 + 1) << 3);
    const float4* e2 = eb + ((j0 + 2) << 3);
    const float4* e3 = eb + ((j0 + 3) << 3);
#pragma unroll
    for (int q = 0; q < 8; ++q) {
      float4 v0 = e0[q], v1 = e1[q], v2 = e2[q], v3 = e3[q];
      // e-sequential FMA chains (bit-identical to R1/R3 per-logit order)
      a0 = fmaf(sv[4 * q + 0], v0.x, a0);
      a0 = fmaf(sv[4 * q + 1], v0.y, a0);
      a0 = fmaf(sv[4 * q + 2], v0.z, a0);
      a0 = fmaf(sv[4 * q + 3], v0.w, a0);
      a1 = fmaf(sv[4 * q + 0], v1.x, a1);
      a1 = fmaf(sv[4 * q + 1], v1.y, a1);
      a1 = fmaf(sv[4 * q + 2], v1.z, a1);
      a1 = fmaf(sv[4 * q + 3], v1.w, a1);
      a2 = fmaf(sv[4 * q + 0], v2.x, a2);
      a2 = fmaf(sv[4 * q + 1], v2.y, a2);
      a2 = fmaf(sv[4 * q + 2], v2.z, a2);
      a2 = fmaf(sv[4 * q + 3], v2.w, a2);
      a3 = fmaf(sv[4 * q + 0], v3.x, a3);
      a3 = fmaf(sv[4 * q + 1], v3.y, a3);
      a3 = fmaf(sv[4 * q + 2], v3.z, a3);
      a3 = fmaf(sv[4 * q + 3], v3.w, a3);
    }

    const float thr = hv[9];
    int p0 = a0 > thr, p1 = a1 > thr, p2 = a2 > thr, p3 = a3 > thr;
    while (__any(p0 | p1 | p2 | p3)) {
      if (p0 | p1 | p2 | p3) {
        float v;
        int jn;
        if (p0) { v = a0; jn = j0; p0 = 0; }
        else if (p1) { v = a1; jn = j0 + 1; p1 = 0; }
        else if (p2) { v = a2; jn = j0 + 2; p2 = 0; }
        else { v = a3; jn = j0 + 3; p3 = 0; }
        TOP10_INSERT(hv, hj, v, jn);
      }
      const float nt = hv[9];
      p0 = p0 && (a0 > nt);
      p1 = p1 && (a1 > nt);
      p2 = p2 && (a2 > nt);
      p3 = p3 && (a3 > nt);
    }
  }

  // ---- publish all 4 lists; every wave re-merges in h order ----------------
#pragma unroll
  for (int k = 0; k < 10; ++k) {
    mv[((w << 6) + lane) * 10 + k] = hv[k];
    mj[((w << 6) + lane) * 10 + k] = hj[k];
  }
  __syncthreads();

  float fv[10];
  int fj[10];
#pragma unroll
  for (int k = 0; k < 10; ++k) { fv[k] = -1e30f; fj[k] = 0; }
  for (int h = 0; h < 4; ++h) {
#pragma unroll
    for (int q = 0; q < 10; ++q) {
      float v = mv[((h << 6) + lane) * 10 + q];
      int jn = mj[((h << 6) + lane) * 10 + q];
      if (v > fv[9]) TOP10_INSERT(fv, fj, v, jn);
    }
  }
  __syncthreads();  // merge reads done -> safe to reuse lds as tile buffers

  // ---- epilogue: wave w writes rows 16w..16w+15 (4 tiles x 4 rows) ---------
  float oval[10];
#pragma unroll
  for (int k = 0; k < 10; ++k) oval[k] = gateb / (1.f + __expf(-fv[k]));

  nf4 z4 = {0.f, 0.f, 0.f, 0.f};
  float* tb = lds + (w << 11);  // 2048 floats (8 KB) per wave
  nf4* tb4 = reinterpret_cast<nf4*>(tb);
  for (int s = 0; s < 4; ++s) {
    const int tt = (w << 2) + s;  // tile 0..15 -> rows 4tt..4tt+3
    asm volatile("s_waitcnt lgkmcnt(0)" ::: "memory");
#pragma unroll
    for (int k = 0; k < 8; ++k) tb4[(k << 6) + lane] = z4;
    asm volatile("s_waitcnt lgkmcnt(0)" ::: "memory");
    if ((lane >> 2) == tt) {
      const int lrow = lane & 3;
#pragma unroll
      for (int k = 0; k < 10; ++k) tb[(lrow << 9) + fj[k]] = oval[k];
    }
    asm volatile("s_waitcnt lgkmcnt(0)" ::: "memory");
    nf4* og = reinterpret_cast<nf4*>(out + ((size_t)(r0 + (tt << 2)) << 9));
#pragma unroll
    for (int k = 0; k < 8; ++k)
      __builtin_nontemporal_store(tb4[(k << 6) + lane], &og[(k << 6) + lane]);
  }
}

extern "C" void kernel_launch(void* const* d_in, const int* in_sizes, int n_in,
                              void* d_out, int out_size, void* d_ws,
                              size_t ws_size, hipStream_t stream) {
  const float* ctx = (const float*)d_in[0];
  const float* emb = (const float*)d_in[1];
  const float* W1 = (const float*)d_in[2];
  const float* b1 = (const float*)d_in[3];
  const float* W2 = (const float*)d_in[4];
  const float* b2 = (const float*)d_in[5];
  const float* Wg = (const float*)d_in[6];
  const float* bg = (const float*)d_in[7];
  float* out = (float*)d_out;
  float* wws = (float*)d_ws;            // 256*32 floats: c^2
  float* gws = wws + BATCH * EMBED_DIM; // 256 floats: gate

  cdm_k1<<<BATCH, 256, 0, stream>>>(ctx, W1, b1, W2, b2, Wg, bg, wws, gws);
  cdm_k2<<<2048, 256, 0, stream>>>(emb, wws, gws, out);
}

// Round 5
// 371.746 us; speedup vs baseline: 1.1102x; 1.1102x over previous
//
#include <hip/hip_runtime.h>
#include <hip/hip_bf16.h>

// CausalDiscoveryModule: B=256, N=512, E=32, IN=512, K=10
// out[b,i,j] = gate_b * sigmoid(logit) on per-(b,i)-row top-10 of j, else 0
// logit = sum_e (c_b^2 * emb_i)[e] * emb_j[e]
//
// R5 (base = R3, the 168us 2-way split; R4's 4-way split regressed):
//  - float2 dots -> v_pk_fma_f32 (halves FMA issue; pairwise even/odd acc)
//  - epilogue direct-to-global: coalesced zero-fill (cached -> L2 lines),
//    vmcnt(0), then 10 scattered dword stores/row merging in L2. No LDS tiles.
//  - symmetric 2-wave blocks (2048 x 128): both waves merge (low half first,
//    strict-> insert of high half => exact jax tie order), each writes 32 rows.
//  - merge LDS [2][10][64] lane-minor: 2-way bank aliasing only (free).

#define NUM_VARS 512
#define EMBED_DIM 32
#define IN_DIM 512
#define BATCH 256

typedef float nf4 __attribute__((ext_vector_type(4)));
typedef float f2 __attribute__((ext_vector_type(2)));

// ---------------- K1: context MLP -> w = c^2 [256][32], gate [256] ----------
__global__ __launch_bounds__(256) void cdm_k1(
    const float* __restrict__ ctx, const float* __restrict__ W1,
    const float* __restrict__ b1, const float* __restrict__ W2,
    const float* __restrict__ b2, const float* __restrict__ Wg,
    const float* __restrict__ bg, float* __restrict__ wws,
    float* __restrict__ gws) {
  const int bb = blockIdx.x;
  const int t = threadIdx.x;
  __shared__ float xs[512];
  __shared__ float psum[32][9];   // +1 pad
  __shared__ float hs[32];
  __shared__ float cs[32];
  const float* x = ctx + (bb << 9);
  xs[t] = x[t];
  xs[t + 256] = x[t + 256];
  __syncthreads();
  {
    const int e = t >> 3, part = t & 7;
    const float* wrow = W1 + e * 512 + part * 64;
    const float* xp = xs + part * 64;
    float a = 0.f;
#pragma unroll
    for (int m = 0; m < 64; ++m) a = fmaf(wrow[m], xp[m], a);
    psum[e][part] = a;
  }
  __syncthreads();
  if (t < 32) {
    float a = 0.f;
#pragma unroll
    for (int p = 0; p < 8; ++p) a += psum[t][p];
    hs[t] = fmaxf(a + b1[t], 0.f);
  }
  __syncthreads();
  if (t < 32) {
    const float* wrow = W2 + (t << 5);
    float a = 0.f;
#pragma unroll
    for (int k = 0; k < 32; ++k) a = fmaf(wrow[k], hs[k], a);
    float c = a + b2[t];
    cs[t] = c;
    wws[(bb << 5) + t] = c * c;
  }
  __syncthreads();
  if (t == 0) {
    float a = 0.f;
#pragma unroll
    for (int k = 0; k < 32; ++k) a = fmaf(Wg[k], cs[k], a);
    float g = a + bg[0];
    gws[bb] = 1.f / (1.f + __expf(-g));
  }
}

// strict-> shift insert: equal values keep earlier-inserted (lower j) above
#define TOP10_INSERT(av, aj, v, jn)                           \
  do {                                                        \
    _Pragma("unroll") for (int k = 9; k >= 1; --k) {          \
      bool gk = (v) > av[k];                                  \
      bool gk1 = (v) > av[k - 1];                             \
      av[k] = gk ? (gk1 ? av[k - 1] : (v)) : av[k];           \
      aj[k] = gk ? (gk1 ? aj[k - 1] : (jn)) : aj[k];          \
    }                                                         \
    bool g0 = (v) > av[0];                                    \
    av[0] = g0 ? (v) : av[0];                                 \
    aj[0] = g0 ? (jn) : aj[0];                                \
  } while (0)

// ---------------- K2: 2-wave block per 64 rows; exact top-10; masked write --
__global__ __launch_bounds__(128, 4) void cdm_k2(
    const float* __restrict__ emb, const float* __restrict__ wws,
    const float* __restrict__ gws, float* __restrict__ out) {
  const int lane = threadIdx.x & 63;
  const int w = threadIdx.x >> 6;    // half 0: j in [0,256), 1: [256,512)
  const int G = __builtin_amdgcn_readfirstlane(blockIdx.x);
  const int r0 = G << 6;             // 64 rows per block, same b
  const int b = r0 >> 9;
  const int i = (r0 + lane) & 511;
  const int jbase = __builtin_amdgcn_readfirstlane(w << 8);

  __shared__ float mvv[2][10][64];   // lane-minor: conflict-free
  __shared__ int mjj[2][10][64];

  // sv2[q] = (c^2)[b] * emb[i] as float2 pairs (per-lane)
  f2 sv2[16];
  {
    const f2* wb = reinterpret_cast<const f2*>(wws + (b << 5));
    const f2* ei = reinterpret_cast<const f2*>(emb + (i << 5));
#pragma unroll
    for (int q = 0; q < 16; ++q) sv2[q] = wb[q] * ei[q];
  }
  const float gateb = gws[b];

  float hv[10];
  int hj[10];
#pragma unroll
  for (int k = 0; k < 10; ++k) { hv[k] = -1e30f; hj[k] = 0; }

  const f2* eb = reinterpret_cast<const f2*>(emb);
  for (int t = 0; t < 64; ++t) {
    const int j0 = jbase + (t << 2);
    const f2* e0 = eb + ((j0 + 0) << 4);
    const f2* e1 = eb + ((j0 + 1) << 4);
    const f2* e2 = eb + ((j0 + 2) << 4);
    const f2* e3 = eb + ((j0 + 3) << 4);
    f2 c0 = {0.f, 0.f}, c1 = {0.f, 0.f}, c2 = {0.f, 0.f}, c3 = {0.f, 0.f};
#pragma unroll
    for (int q = 0; q < 16; ++q) {
      c0 += sv2[q] * e0[q];   // v_pk_fma_f32
      c1 += sv2[q] * e1[q];
      c2 += sv2[q] * e2[q];
      c3 += sv2[q] * e3[q];
    }
    float a0 = c0.x + c0.y, a1 = c1.x + c1.y;
    float a2 = c2.x + c2.y, a3 = c3.x + c3.y;

    const float thr = hv[9];
    int p0 = a0 > thr, p1 = a1 > thr, p2 = a2 > thr, p3 = a3 > thr;
    while (__any(p0 | p1 | p2 | p3)) {
      if (p0 | p1 | p2 | p3) {
        float v;
        int jn;
        if (p0) { v = a0; jn = j0; p0 = 0; }
        else if (p1) { v = a1; jn = j0 + 1; p1 = 0; }
        else if (p2) { v = a2; jn = j0 + 2; p2 = 0; }
        else { v = a3; jn = j0 + 3; p3 = 0; }
        TOP10_INSERT(hv, hj, v, jn);
      }
      const float nt = hv[9];
      p0 = p0 && (a0 > nt);
      p1 = p1 && (a1 > nt);
      p2 = p2 && (a2 > nt);
      p3 = p3 && (a3 > nt);
    }
  }

  // ---- publish; both waves build final list (low half first) ---------------
#pragma unroll
  for (int k = 0; k < 10; ++k) {
    mvv[w][k][lane] = hv[k];
    mjj[w][k][lane] = hj[k];
  }
  __syncthreads();

  float fv[10];
  int fj[10];
  if (w == 0) {
    // own list IS the low half
#pragma unroll
    for (int k = 0; k < 10; ++k) { fv[k] = hv[k]; fj[k] = hj[k]; }
    // insert partner (high half) with strict >
#pragma unroll
    for (int q = 0; q < 10; ++q) {
      float v = mvv[1][q][lane];
      int jn = mjj[1][q][lane];
      if (v > fv[9]) TOP10_INSERT(fv, fj, v, jn);
    }
  } else {
    // base = partner (low half), then insert own (high half)
#pragma unroll
    for (int k = 0; k < 10; ++k) { fv[k] = mvv[0][k][lane]; fj[k] = mjj[0][k][lane]; }
#pragma unroll
    for (int q = 0; q < 10; ++q) {
      float v = hv[q];
      int jn = hj[q];
      if (v > fv[9]) TOP10_INSERT(fv, fj, v, jn);
    }
  }

  // ---- epilogue: zero 32 rows coalesced (cached), wait, scatter 10/row -----
  float oval[10];
#pragma unroll
  for (int k = 0; k < 10; ++k) oval[k] = gateb / (1.f + __expf(-fv[k]));

  nf4 z4 = {0.f, 0.f, 0.f, 0.f};
  nf4* zb4 = reinterpret_cast<nf4*>(out + ((size_t)(r0 + (w << 5)) << 9));
#pragma unroll 8
  for (int k = 0; k < 64; ++k) zb4[(k << 6) + lane] = z4;
  asm volatile("s_waitcnt vmcnt(0)" ::: "memory");
  if ((lane >> 5) == w) {
    float* rbase = out + ((size_t)(r0 + lane) << 9);
#pragma unroll
    for (int k = 0; k < 10; ++k) rbase[fj[k]] = oval[k];
  }
}

extern "C" void kernel_launch(void* const* d_in, const int* in_sizes, int n_in,
                              void* d_out, int out_size, void* d_ws,
                              size_t ws_size, hipStream_t stream) {
  const float* ctx = (const float*)d_in[0];
  const float* emb = (const float*)d_in[1];
  const float* W1 = (const float*)d_in[2];
  const float* b1 = (const float*)d_in[3];
  const float* W2 = (const float*)d_in[4];
  const float* b2 = (const float*)d_in[5];
  const float* Wg = (const float*)d_in[6];
  const float* bg = (const float*)d_in[7];
  float* out = (float*)d_out;
  float* wws = (float*)d_ws;            // 256*32 floats: c^2
  float* gws = wws + BATCH * EMBED_DIM; // 256 floats: gate

  cdm_k1<<<BATCH, 256, 0, stream>>>(ctx, W1, b1, W2, b2, Wg, bg, wws, gws);
  cdm_k2<<<2048, 128, 0, stream>>>(emb, wws, gws, out);
}